// Round 1
// baseline (798.694 us; speedup 1.0000x reference)
//
#include <hip/hip_runtime.h>

#define N_NODES 100000
#define N_USERS 50000
#define F_DIM 256
#define H 128
#define N_EDGES 800000
#define BATCH 4096
#define LN_EPS 1e-5f

// ---------------------------------------------------------------------------
// Small utility kernels
// ---------------------------------------------------------------------------

// Pack W [H x K] row-major into Wp [K/4][H][4] so that a thread reading
// float4 Wp4[kb*H + j] gets W[j, 4kb..4kb+3] (coalesced across j).
__global__ void pack_w_kernel(const float* __restrict__ W, float* __restrict__ Wp,
                              int K, int total) {
    int idx = blockIdx.x * 256 + threadIdx.x;
    if (idx >= total) return;
    int ff = idx & 3;
    int j  = (idx >> 2) & (H - 1);
    int kb = idx >> 9;          // / (4*H)
    Wp[idx] = W[j * K + kb * 4 + ff];
}

__global__ void zero_ints_kernel(int* __restrict__ p, int n) {
    int i = blockIdx.x * 256 + threadIdx.x;
    if (i < n) p[i] = 0;
}

__global__ void count_edges_kernel(const int* __restrict__ row, int* __restrict__ counts) {
    int e = blockIdx.x * 256 + threadIdx.x;
    if (e < N_EDGES) atomicAdd(&counts[row[e]], 1);
}

// 1024 elements per block, 256 threads x 4 elements each.
__global__ void scan_pass1_kernel(const int* __restrict__ counts, int* __restrict__ out,
                                  int* __restrict__ blockSums, int n) {
    __shared__ int lds[256];
    int b = blockIdx.x;
    int t = threadIdx.x;
    int base = b * 1024 + t * 4;
    int v0 = (base + 0 < n) ? counts[base + 0] : 0;
    int v1 = (base + 1 < n) ? counts[base + 1] : 0;
    int v2 = (base + 2 < n) ? counts[base + 2] : 0;
    int v3 = (base + 3 < n) ? counts[base + 3] : 0;
    int tsum = v0 + v1 + v2 + v3;
    lds[t] = tsum;
    __syncthreads();
    for (int off = 1; off < 256; off <<= 1) {
        int x = 0;
        if (t >= off) x = lds[t - off];
        __syncthreads();
        lds[t] += x;
        __syncthreads();
    }
    int excl = (t > 0) ? lds[t - 1] : 0;
    if (t == 255) blockSums[b] = lds[255];
    int e0 = excl, e1 = e0 + v0, e2 = e1 + v1, e3 = e2 + v2;
    if (base + 0 < n) out[base + 0] = e0;
    if (base + 1 < n) out[base + 1] = e1;
    if (base + 2 < n) out[base + 2] = e2;
    if (base + 3 < n) out[base + 3] = e3;
}

__global__ void scan_pass2_kernel(int* __restrict__ blockSums, int nb) {
    if (threadIdx.x == 0 && blockIdx.x == 0) {
        int run = 0;
        for (int i = 0; i < nb; ++i) {
            int t = blockSums[i];
            blockSums[i] = run;
            run += t;
        }
    }
}

__global__ void scan_pass3_kernel(int* __restrict__ row_start, int* __restrict__ cursor,
                                  const int* __restrict__ blockSums, int n) {
    int b = blockIdx.x;
    int t = threadIdx.x;
    int base = b * 1024 + t * 4;
    int add = blockSums[b];
    #pragma unroll
    for (int k = 0; k < 4; ++k) {
        int i = base + k;
        if (i < n) {
            int rs = row_start[i] + add;
            row_start[i] = rs;
            cursor[i] = rs;
        }
    }
}

__global__ void scatter_edges_kernel(const int* __restrict__ row, const int* __restrict__ col,
                                     const float* __restrict__ vals, int* __restrict__ cursor,
                                     int* __restrict__ ecol, float* __restrict__ evals) {
    int e = blockIdx.x * 256 + threadIdx.x;
    if (e >= N_EDGES) return;
    int r = row[e];
    int pos = atomicAdd(&cursor[r], 1);
    ecol[pos] = col[e];
    evals[pos] = vals[e];
}

// ---------------------------------------------------------------------------
// Proj GEMM: h0[n,j] = sum_f A[n,f] * W_proj[j,f] + b_proj[j]
// A: [N_NODES, 256], Wtp packed [64][128][4], out: [N_NODES, 128]
// block = 256 threads, 16 rows per block. thread: col j = tid&127, 8 rows.
// ---------------------------------------------------------------------------
__global__ __launch_bounds__(256) void proj_gemm_kernel(
        const float* __restrict__ A, const float* __restrict__ Wtp,
        const float* __restrict__ bias, float* __restrict__ out) {
    __shared__ float As[16 * 256];
    const int row0 = blockIdx.x * 16;
    const int tid = threadIdx.x;

    const float4* Ag = (const float4*)(A + (size_t)row0 * F_DIM);
    float4* Asw = (float4*)As;
    #pragma unroll
    for (int i = 0; i < 4; ++i) Asw[tid + i * 256] = Ag[tid + i * 256];
    __syncthreads();

    const int j = tid & 127;
    const int rh = tid >> 7;   // 0 or 1
    const float4* Wv = (const float4*)Wtp;
    const float4* As4 = (const float4*)As;

    float acc[8];
    #pragma unroll
    for (int k = 0; k < 8; ++k) acc[k] = 0.f;

    for (int fb = 0; fb < F_DIM / 4; ++fb) {
        float4 wv = Wv[fb * 128 + j];
        #pragma unroll
        for (int k = 0; k < 8; ++k) {
            float4 av = As4[(rh + 2 * k) * 64 + fb];
            acc[k] += av.x * wv.x + av.y * wv.y + av.z * wv.z + av.w * wv.w;
        }
    }
    float bj = bias[j];
    #pragma unroll
    for (int k = 0; k < 8; ++k)
        out[(size_t)(row0 + rh + 2 * k) * H + j] = acc[k] + bj;
}

// ---------------------------------------------------------------------------
// SPMM: out[r,:] = sum_{e in row r} val[e] * hin[col[e],:]
// one wave per row, float2 per lane.
// ---------------------------------------------------------------------------
__global__ __launch_bounds__(256) void spmm_kernel(
        const float* __restrict__ hin, float* __restrict__ hout,
        const int* __restrict__ row_start, const int* __restrict__ ecol,
        const float* __restrict__ evals) {
    const int wave = threadIdx.x >> 6;
    const int lane = threadIdx.x & 63;
    const int row = blockIdx.x * 4 + wave;
    if (row >= N_NODES) return;
    const int s = row_start[row];
    const int e = (row + 1 < N_NODES) ? row_start[row + 1] : N_EDGES;
    float2 acc = make_float2(0.f, 0.f);
    const float2* h2 = (const float2*)hin;
    for (int p = s; p < e; ++p) {
        int c = ecol[p];
        float vv = evals[p];
        float2 hv = h2[(size_t)c * 64 + lane];
        acc.x += vv * hv.x;
        acc.y += vv * hv.y;
    }
    ((float2*)hout)[(size_t)row * 64 + lane] = acc;
}

// ---------------------------------------------------------------------------
// Fused MLP layer: out[n,:] = LN(relu(T[n,:] @ W.T + b)) * g + beta
// T: [N,128], Wp packed [32][128][4]. 16 rows per block.
// ---------------------------------------------------------------------------
__global__ __launch_bounds__(256) void mlp_fused_kernel(
        const float* __restrict__ T, const float* __restrict__ Wp,
        const float* __restrict__ bias, const float* __restrict__ g,
        const float* __restrict__ beta, float* __restrict__ out) {
    __shared__ float Ts[16 * 128];
    __shared__ float red[4][8][2];
    const int row0 = blockIdx.x * 16;
    const int tid = threadIdx.x;

    const float4* Tg = (const float4*)(T + (size_t)row0 * H);
    float4* Tw = (float4*)Ts;
    #pragma unroll
    for (int i = 0; i < 2; ++i) Tw[tid + i * 256] = Tg[tid + i * 256];
    __syncthreads();

    const int j = tid & 127;
    const int rh = tid >> 7;
    const float4* Wv = (const float4*)Wp;
    const float4* Ts4 = (const float4*)Ts;

    float acc[8];
    #pragma unroll
    for (int k = 0; k < 8; ++k) acc[k] = 0.f;

    for (int kb = 0; kb < H / 4; ++kb) {
        float4 wv = Wv[kb * 128 + j];
        #pragma unroll
        for (int k = 0; k < 8; ++k) {
            float4 tv = Ts4[(rh + 2 * k) * 32 + kb];
            acc[k] += tv.x * wv.x + tv.y * wv.y + tv.z * wv.z + tv.w * wv.w;
        }
    }

    const float bj = bias[j], gj = g[j], betj = beta[j];
    const int wave = tid >> 6;
    float v[8];
    float s1[8], s2[8];
    #pragma unroll
    for (int k = 0; k < 8; ++k) {
        float x = fmaxf(acc[k] + bj, 0.f);
        v[k] = x;
        float a = x, q = x * x;
        #pragma unroll
        for (int off = 32; off > 0; off >>= 1) {
            a += __shfl_xor(a, off);
            q += __shfl_xor(q, off);
        }
        s1[k] = a; s2[k] = q;
    }
    if ((tid & 63) == 0) {
        #pragma unroll
        for (int k = 0; k < 8; ++k) { red[wave][k][0] = s1[k]; red[wave][k][1] = s2[k]; }
    }
    __syncthreads();
    #pragma unroll
    for (int k = 0; k < 8; ++k) {
        float ts = red[wave][k][0] + red[wave ^ 1][k][0];
        float tq = red[wave][k][1] + red[wave ^ 1][k][1];
        float mu = ts * (1.f / 128.f);
        float var = tq * (1.f / 128.f) - mu * mu;
        float r = rsqrtf(var + LN_EPS);
        out[(size_t)(row0 + rh + 2 * k) * H + j] = (v[k] - mu) * r * gj + betj;
    }
}

// ---------------------------------------------------------------------------
// Scoring: out[b] = gb + user_bias[u] + item_bias[i] + dot(user_emb[u],
//                     hfinal[i] + h0[i] + item_id_emb[i])
// one wave per batch element.
// ---------------------------------------------------------------------------
__global__ __launch_bounds__(256) void score_kernel(
        const float* __restrict__ hf, const float* __restrict__ h0,
        const float* __restrict__ iie, const float* __restrict__ uemb,
        const int* __restrict__ uidx, const int* __restrict__ iidx,
        const float* __restrict__ ubias, const float* __restrict__ ibias,
        const float* __restrict__ gbias, float* __restrict__ out) {
    const int wave = threadIdx.x >> 6;
    const int lane = threadIdx.x & 63;
    const int b = blockIdx.x * 4 + wave;
    if (b >= BATCH) return;
    const int u = uidx[b];
    const int it = iidx[b];
    const float2* ue = (const float2*)(uemb + (size_t)u * H);
    const float2* e1 = (const float2*)(hf + (size_t)it * H);
    const float2* e2 = (const float2*)(h0 + (size_t)it * H);
    const float2* e3 = (const float2*)(iie + (size_t)it * H);
    float2 a = ue[lane], x1 = e1[lane], x2 = e2[lane], x3 = e3[lane];
    float p = a.x * (x1.x + x2.x + x3.x) + a.y * (x1.y + x2.y + x3.y);
    #pragma unroll
    for (int off = 32; off > 0; off >>= 1) p += __shfl_xor(p, off);
    if (lane == 0) out[b] = gbias[0] + ubias[u] + ibias[it] + p;
}

// ---------------------------------------------------------------------------

extern "C" void kernel_launch(void* const* d_in, const int* in_sizes, int n_in,
                              void* d_out, int out_size, void* d_ws, size_t ws_size,
                              hipStream_t stream) {
    const float* node_features = (const float*)d_in[0];
    const int*   adj_row       = (const int*)d_in[1];
    const int*   adj_col       = (const int*)d_in[2];
    const float* adj_vals      = (const float*)d_in[3];
    const int*   user_idx      = (const int*)d_in[4];
    const int*   item_idx      = (const int*)d_in[5];
    const float* W_proj        = (const float*)d_in[6];
    const float* b_proj        = (const float*)d_in[7];
    const float* W1            = (const float*)d_in[8];
    const float* b1            = (const float*)d_in[9];
    const float* W2            = (const float*)d_in[10];
    const float* b2            = (const float*)d_in[11];
    const float* ln_g          = (const float*)d_in[12];
    const float* ln_b          = (const float*)d_in[13];
    const float* user_emb      = (const float*)d_in[14];
    const float* item_id_emb   = (const float*)d_in[15];
    const float* user_bias     = (const float*)d_in[16];
    const float* item_bias     = (const float*)d_in[17];
    const float* global_bias   = (const float*)d_in[18];
    float* outp = (float*)d_out;

    char* ws = (char*)d_ws;
    size_t off = 0;
    auto alloc = [&](size_t bytes) -> void* {
        void* p = ws + off;
        off = (off + bytes + 255) & ~(size_t)255;
        return p;
    };

    float* h0  = (float*)alloc(sizeof(float) * (size_t)N_NODES * H);
    float* hA  = (float*)alloc(sizeof(float) * (size_t)N_NODES * H);
    float* hB  = (float*)alloc(sizeof(float) * (size_t)N_NODES * H);
    float* Wtp = (float*)alloc(sizeof(float) * F_DIM * H);
    float* W1p = (float*)alloc(sizeof(float) * H * H);
    float* W2p = (float*)alloc(sizeof(float) * H * H);
    int* counts    = (int*)alloc(sizeof(int) * N_NODES);
    int* row_start = (int*)alloc(sizeof(int) * N_NODES);
    int* cursor    = (int*)alloc(sizeof(int) * N_NODES);
    int* blockSums = (int*)alloc(sizeof(int) * 128);
    int* ecol      = (int*)alloc(sizeof(int) * N_EDGES);
    float* evals   = (float*)alloc(sizeof(float) * N_EDGES);

    const int NB = (N_NODES + 1023) / 1024;  // 98

    // weight packing
    pack_w_kernel<<<(F_DIM * H + 255) / 256, 256, 0, stream>>>(W_proj, Wtp, F_DIM, F_DIM * H);
    pack_w_kernel<<<(H * H + 255) / 256, 256, 0, stream>>>(W1, W1p, H, H * H);
    pack_w_kernel<<<(H * H + 255) / 256, 256, 0, stream>>>(W2, W2p, H, H * H);

    // CSR build
    zero_ints_kernel<<<(N_NODES + 255) / 256, 256, 0, stream>>>(counts, N_NODES);
    count_edges_kernel<<<N_EDGES / 256, 256, 0, stream>>>(adj_row, counts);
    scan_pass1_kernel<<<NB, 256, 0, stream>>>(counts, row_start, blockSums, N_NODES);
    scan_pass2_kernel<<<1, 64, 0, stream>>>(blockSums, NB);
    scan_pass3_kernel<<<NB, 256, 0, stream>>>(row_start, cursor, blockSums, N_NODES);
    scatter_edges_kernel<<<N_EDGES / 256, 256, 0, stream>>>(adj_row, adj_col, adj_vals,
                                                            cursor, ecol, evals);

    // proj
    proj_gemm_kernel<<<N_NODES / 16, 256, 0, stream>>>(node_features, Wtp, b_proj, h0);

    // layer 1
    spmm_kernel<<<N_NODES / 4, 256, 0, stream>>>(h0, hA, row_start, ecol, evals);
    mlp_fused_kernel<<<N_NODES / 16, 256, 0, stream>>>(hA, W1p, b1, ln_g, ln_b, hB);

    // layer 2
    spmm_kernel<<<N_NODES / 4, 256, 0, stream>>>(hB, hA, row_start, ecol, evals);
    mlp_fused_kernel<<<N_NODES / 16, 256, 0, stream>>>(hA, W2p, b2, ln_g, ln_b, hB);

    // scoring
    score_kernel<<<BATCH / 4, 256, 0, stream>>>(hB, h0, item_id_emb, user_emb,
                                                user_idx, item_idx, user_bias,
                                                item_bias, global_bias, outp);
}

// Round 2
// 562.444 us; speedup vs baseline: 1.4200x; 1.4200x over previous
//
#include <hip/hip_runtime.h>

#define N_NODES 100000
#define N_USERS 50000
#define F_DIM 256
#define H 128
#define N_EDGES 800000
#define BATCH 4096
#define LN_EPS 1e-5f

typedef __attribute__((ext_vector_type(8))) short short8_t;
typedef __attribute__((ext_vector_type(8))) __bf16 bf16x8;
typedef __attribute__((ext_vector_type(4))) float f32x4;

__device__ inline unsigned short f2bf(float f) {
    unsigned int u = __builtin_bit_cast(unsigned int, f);
    unsigned int r = (u + 0x7fffu + ((u >> 16) & 1u)) >> 16;
    return (unsigned short)r;
}
__device__ inline float bf_lo(unsigned int u) {
    unsigned int x = u << 16; return __builtin_bit_cast(float, x);
}
__device__ inline float bf_hi(unsigned int u) {
    unsigned int x = u & 0xFFFF0000u; return __builtin_bit_cast(float, x);
}

// ---------------------------------------------------------------------------
// Weight pack: W [H x K] fp32 row-major -> bf16 fragments in wave-load order.
// Element idx: i=idx&7, lane=(idx>>3)&63, c=(idx>>9)&7, ks=idx>>12.
// frag elem i = W[c*16 + (lane&15)][ks*32 + (lane>>4)*8 + i]
// ---------------------------------------------------------------------------
__global__ void pack_wfrag_kernel(const float* __restrict__ W, short* __restrict__ out,
                                  int K, int total) {
    int idx = blockIdx.x * 256 + threadIdx.x;
    if (idx >= total) return;
    int i    = idx & 7;
    int lane = (idx >> 3) & 63;
    int c    = (idx >> 9) & 7;
    int ks   = idx >> 12;
    int j = c * 16 + (lane & 15);
    int k = ks * 32 + (lane >> 4) * 8 + i;
    out[idx] = (short)f2bf(W[j * K + k]);
}

// ---------------------------------------------------------------------------
// CSR build
// ---------------------------------------------------------------------------
__global__ void zero_ints_kernel(int* __restrict__ p, int n) {
    int i = blockIdx.x * 256 + threadIdx.x;
    if (i < n) p[i] = 0;
}

__global__ void count_edges_kernel(const int* __restrict__ row, int* __restrict__ counts) {
    int e = blockIdx.x * 256 + threadIdx.x;
    if (e < N_EDGES) atomicAdd(&counts[row[e]], 1);
}

__global__ void scan_pass1_kernel(const int* __restrict__ counts, int* __restrict__ out,
                                  int* __restrict__ blockSums, int n) {
    __shared__ int lds[256];
    int b = blockIdx.x;
    int t = threadIdx.x;
    int base = b * 1024 + t * 4;
    int v0 = (base + 0 < n) ? counts[base + 0] : 0;
    int v1 = (base + 1 < n) ? counts[base + 1] : 0;
    int v2 = (base + 2 < n) ? counts[base + 2] : 0;
    int v3 = (base + 3 < n) ? counts[base + 3] : 0;
    int tsum = v0 + v1 + v2 + v3;
    lds[t] = tsum;
    __syncthreads();
    for (int off = 1; off < 256; off <<= 1) {
        int x = 0;
        if (t >= off) x = lds[t - off];
        __syncthreads();
        lds[t] += x;
        __syncthreads();
    }
    int excl = (t > 0) ? lds[t - 1] : 0;
    if (t == 255) blockSums[b] = lds[255];
    int e0 = excl, e1 = e0 + v0, e2 = e1 + v1, e3 = e2 + v2;
    if (base + 0 < n) out[base + 0] = e0;
    if (base + 1 < n) out[base + 1] = e1;
    if (base + 2 < n) out[base + 2] = e2;
    if (base + 3 < n) out[base + 3] = e3;
}

__global__ void scan_pass2_kernel(int* __restrict__ blockSums, int nb) {
    if (threadIdx.x == 0 && blockIdx.x == 0) {
        int run = 0;
        for (int i = 0; i < nb; ++i) {
            int t = blockSums[i];
            blockSums[i] = run;
            run += t;
        }
    }
}

__global__ void scan_pass3_kernel(int* __restrict__ row_start, int* __restrict__ cursor,
                                  const int* __restrict__ blockSums, int n) {
    int b = blockIdx.x;
    int t = threadIdx.x;
    int base = b * 1024 + t * 4;
    int add = blockSums[b];
    #pragma unroll
    for (int k = 0; k < 4; ++k) {
        int i = base + k;
        if (i < n) {
            int rs = row_start[i] + add;
            row_start[i] = rs;
            cursor[i] = rs;
        }
    }
}

__global__ void scatter_edges_kernel(const int* __restrict__ row, const int* __restrict__ col,
                                     const float* __restrict__ vals, int* __restrict__ cursor,
                                     int* __restrict__ ecol, float* __restrict__ evals) {
    int e = blockIdx.x * 256 + threadIdx.x;
    if (e >= N_EDGES) return;
    int r = row[e];
    int pos = atomicAdd(&cursor[r], 1);
    ecol[pos] = col[e];
    evals[pos] = vals[e];
}

// ---------------------------------------------------------------------------
// Proj: h0[n,j] = bf16( sum_f A[n,f]*Wp[j,f] + b[j] ).  MFMA 16x16x32 bf16.
// One wave per 16-row tile; 8 col-tiles x 8 k-steps.
// A read fp32 from global in fragment order, cvt in-register.
// B read from pre-packed fragment buffer (coalesced 1KB wave loads).
// ---------------------------------------------------------------------------
__global__ __launch_bounds__(256) void proj_mfma_kernel(
        const float* __restrict__ A, const short* __restrict__ Bp,
        const float* __restrict__ bias, unsigned short* __restrict__ out) {
    const int tid  = threadIdx.x;
    const int lane = tid & 63;
    const int tile = blockIdx.x * 4 + (tid >> 6);
    if (tile >= N_NODES / 16) return;
    const int row0 = tile * 16;
    const int lrow = lane & 15;
    const int lk   = lane >> 4;

    const short8_t* Bv = (const short8_t*)Bp;
    f32x4 acc[8];
    #pragma unroll
    for (int c = 0; c < 8; ++c) acc[c] = (f32x4)(0.f);

    const float* Arow = A + (size_t)(row0 + lrow) * F_DIM + lk * 8;
    #pragma unroll 2
    for (int ks = 0; ks < 8; ++ks) {
        const float4* ap = (const float4*)(Arow + ks * 32);
        float4 a0 = ap[0], a1 = ap[1];
        short8_t af;
        af[0] = (short)f2bf(a0.x); af[1] = (short)f2bf(a0.y);
        af[2] = (short)f2bf(a0.z); af[3] = (short)f2bf(a0.w);
        af[4] = (short)f2bf(a1.x); af[5] = (short)f2bf(a1.y);
        af[6] = (short)f2bf(a1.z); af[7] = (short)f2bf(a1.w);
        bf16x8 av = __builtin_bit_cast(bf16x8, af);
        const short8_t* bp = Bv + (size_t)(ks * 8) * 64 + lane;
        #pragma unroll
        for (int c = 0; c < 8; ++c) {
            bf16x8 bv = __builtin_bit_cast(bf16x8, bp[c * 64]);
            acc[c] = __builtin_amdgcn_mfma_f32_16x16x32_bf16(av, bv, acc[c], 0, 0, 0);
        }
    }
    const int orow = row0 + lk * 4;
    #pragma unroll
    for (int c = 0; c < 8; ++c) {
        float bj = bias[c * 16 + lrow];
        #pragma unroll
        for (int r = 0; r < 4; ++r)
            out[(size_t)(orow + r) * H + c * 16 + lrow] = f2bf(acc[c][r] + bj);
    }
}

// ---------------------------------------------------------------------------
// SPMM (bf16): out[r,:] = bf16( sum_e val[e] * hin[col[e],:] )
// one wave per row; lane holds 2 bf16 (4B) -> 256B coalesced gather per edge.
// ---------------------------------------------------------------------------
__global__ __launch_bounds__(256) void spmm_bf16_kernel(
        const unsigned short* __restrict__ hin, unsigned short* __restrict__ hout,
        const int* __restrict__ row_start, const int* __restrict__ ecol,
        const float* __restrict__ evals) {
    const int wave = threadIdx.x >> 6;
    const int lane = threadIdx.x & 63;
    const int row = blockIdx.x * 4 + wave;
    if (row >= N_NODES) return;
    const int s = row_start[row];
    const int e = (row + 1 < N_NODES) ? row_start[row + 1] : N_EDGES;
    float ax = 0.f, ay = 0.f;
    const unsigned int* h32 = (const unsigned int*)hin;
    for (int p = s; p < e; ++p) {
        int c = ecol[p];
        float vv = evals[p];
        unsigned int hb = h32[(size_t)c * 64 + lane];
        ax += vv * bf_lo(hb);
        ay += vv * bf_hi(hb);
    }
    unsigned int w = (unsigned int)f2bf(ax) | ((unsigned int)f2bf(ay) << 16);
    ((unsigned int*)hout)[(size_t)row * 64 + lane] = w;
}

// ---------------------------------------------------------------------------
// Fused MLP: out = bf16( LN(relu(X @ W.T + b)) * g + beta ).  MFMA, K=128.
// ---------------------------------------------------------------------------
__global__ __launch_bounds__(256) void mlp_mfma_kernel(
        const unsigned short* __restrict__ X, const short* __restrict__ Bp,
        const float* __restrict__ bias, const float* __restrict__ g,
        const float* __restrict__ beta, unsigned short* __restrict__ out) {
    const int tid  = threadIdx.x;
    const int lane = tid & 63;
    const int tile = blockIdx.x * 4 + (tid >> 6);
    if (tile >= N_NODES / 16) return;
    const int row0 = tile * 16;
    const int lrow = lane & 15;
    const int lk   = lane >> 4;

    const short8_t* Bv = (const short8_t*)Bp;
    const short8_t* Xv = (const short8_t*)(X + (size_t)(row0 + lrow) * H + lk * 8);

    f32x4 acc[8];
    #pragma unroll
    for (int c = 0; c < 8; ++c) acc[c] = (f32x4)(0.f);

    #pragma unroll
    for (int ks = 0; ks < 4; ++ks) {
        bf16x8 av = __builtin_bit_cast(bf16x8, Xv[ks * 4]);
        const short8_t* bp = Bv + (size_t)(ks * 8) * 64 + lane;
        #pragma unroll
        for (int c = 0; c < 8; ++c) {
            bf16x8 bv = __builtin_bit_cast(bf16x8, bp[c * 64]);
            acc[c] = __builtin_amdgcn_mfma_f32_16x16x32_bf16(av, bv, acc[c], 0, 0, 0);
        }
    }

    // bias + relu + LN over the 128 cols of each of this lane-group's 4 rows.
    float s1[4] = {0.f, 0.f, 0.f, 0.f};
    float s2[4] = {0.f, 0.f, 0.f, 0.f};
    #pragma unroll
    for (int c = 0; c < 8; ++c) {
        float bj = bias[c * 16 + lrow];
        #pragma unroll
        for (int r = 0; r < 4; ++r) {
            float x = fmaxf(acc[c][r] + bj, 0.f);
            acc[c][r] = x;
            s1[r] += x;
            s2[r] += x * x;
        }
    }
    #pragma unroll
    for (int r = 0; r < 4; ++r) {
        #pragma unroll
        for (int off = 1; off < 16; off <<= 1) {
            s1[r] += __shfl_xor(s1[r], off);
            s2[r] += __shfl_xor(s2[r], off);
        }
    }
    float mu[4], rr[4];
    #pragma unroll
    for (int r = 0; r < 4; ++r) {
        mu[r] = s1[r] * (1.f / 128.f);
        float var = s2[r] * (1.f / 128.f) - mu[r] * mu[r];
        rr[r] = rsqrtf(var + LN_EPS);
    }
    const int orow = row0 + lk * 4;
    #pragma unroll
    for (int c = 0; c < 8; ++c) {
        float gj  = g[c * 16 + lrow];
        float bj2 = beta[c * 16 + lrow];
        #pragma unroll
        for (int r = 0; r < 4; ++r)
            out[(size_t)(orow + r) * H + c * 16 + lrow] =
                f2bf((acc[c][r] - mu[r]) * rr[r] * gj + bj2);
    }
}

// ---------------------------------------------------------------------------
// Scoring: out[b] = gb + ub[u] + ib[i] + dot(uemb[u], hf[i] + h0[i] + iie[i])
// ---------------------------------------------------------------------------
__global__ __launch_bounds__(256) void score_kernel(
        const unsigned short* __restrict__ hf, const unsigned short* __restrict__ h0,
        const float* __restrict__ iie, const float* __restrict__ uemb,
        const int* __restrict__ uidx, const int* __restrict__ iidx,
        const float* __restrict__ ubias, const float* __restrict__ ibias,
        const float* __restrict__ gbias, float* __restrict__ out) {
    const int wave = threadIdx.x >> 6;
    const int lane = threadIdx.x & 63;
    const int b = blockIdx.x * 4 + wave;
    if (b >= BATCH) return;
    const int u  = uidx[b];
    const int it = iidx[b];
    unsigned int b1 = ((const unsigned int*)hf)[(size_t)it * 64 + lane];
    unsigned int b2 = ((const unsigned int*)h0)[(size_t)it * 64 + lane];
    float2 x3 = ((const float2*)(iie + (size_t)it * H))[lane];
    float2 a  = ((const float2*)(uemb + (size_t)u * H))[lane];
    float p = a.x * (bf_lo(b1) + bf_lo(b2) + x3.x) +
              a.y * (bf_hi(b1) + bf_hi(b2) + x3.y);
    #pragma unroll
    for (int off = 32; off > 0; off >>= 1) p += __shfl_xor(p, off);
    if (lane == 0) out[b] = gbias[0] + ubias[u] + ibias[it] + p;
}

// ---------------------------------------------------------------------------

extern "C" void kernel_launch(void* const* d_in, const int* in_sizes, int n_in,
                              void* d_out, int out_size, void* d_ws, size_t ws_size,
                              hipStream_t stream) {
    const float* node_features = (const float*)d_in[0];
    const int*   adj_row       = (const int*)d_in[1];
    const int*   adj_col       = (const int*)d_in[2];
    const float* adj_vals      = (const float*)d_in[3];
    const int*   user_idx      = (const int*)d_in[4];
    const int*   item_idx      = (const int*)d_in[5];
    const float* W_proj        = (const float*)d_in[6];
    const float* b_proj        = (const float*)d_in[7];
    const float* W1            = (const float*)d_in[8];
    const float* b1            = (const float*)d_in[9];
    const float* W2            = (const float*)d_in[10];
    const float* b2            = (const float*)d_in[11];
    const float* ln_g          = (const float*)d_in[12];
    const float* ln_b          = (const float*)d_in[13];
    const float* user_emb      = (const float*)d_in[14];
    const float* item_id_emb   = (const float*)d_in[15];
    const float* user_bias     = (const float*)d_in[16];
    const float* item_bias     = (const float*)d_in[17];
    const float* global_bias   = (const float*)d_in[18];
    float* outp = (float*)d_out;

    char* ws = (char*)d_ws;
    size_t off = 0;
    auto alloc = [&](size_t bytes) -> void* {
        void* p = ws + off;
        off = (off + bytes + 255) & ~(size_t)255;
        return p;
    };

    unsigned short* h0 = (unsigned short*)alloc(sizeof(short) * (size_t)N_NODES * H);
    unsigned short* hA = (unsigned short*)alloc(sizeof(short) * (size_t)N_NODES * H);
    unsigned short* hB = (unsigned short*)alloc(sizeof(short) * (size_t)N_NODES * H);
    short* Wpp = (short*)alloc(sizeof(short) * F_DIM * H);
    short* W1p = (short*)alloc(sizeof(short) * H * H);
    short* W2p = (short*)alloc(sizeof(short) * H * H);
    int* counts    = (int*)alloc(sizeof(int) * N_NODES);
    int* row_start = (int*)alloc(sizeof(int) * N_NODES);
    int* cursor    = (int*)alloc(sizeof(int) * N_NODES);
    int* blockSums = (int*)alloc(sizeof(int) * 128);
    int* ecol      = (int*)alloc(sizeof(int) * N_EDGES);
    float* evals   = (float*)alloc(sizeof(float) * N_EDGES);

    const int NB = (N_NODES + 1023) / 1024;  // 98

    // weight packing (bf16 fragment order)
    pack_wfrag_kernel<<<(F_DIM * H + 255) / 256, 256, 0, stream>>>(W_proj, Wpp, F_DIM, F_DIM * H);
    pack_wfrag_kernel<<<(H * H + 255) / 256, 256, 0, stream>>>(W1, W1p, H, H * H);
    pack_wfrag_kernel<<<(H * H + 255) / 256, 256, 0, stream>>>(W2, W2p, H, H * H);

    // CSR build
    zero_ints_kernel<<<(N_NODES + 255) / 256, 256, 0, stream>>>(counts, N_NODES);
    count_edges_kernel<<<N_EDGES / 256, 256, 0, stream>>>(adj_row, counts);
    scan_pass1_kernel<<<NB, 256, 0, stream>>>(counts, row_start, blockSums, N_NODES);
    scan_pass2_kernel<<<1, 64, 0, stream>>>(blockSums, NB);
    scan_pass3_kernel<<<NB, 256, 0, stream>>>(row_start, cursor, blockSums, N_NODES);
    scatter_edges_kernel<<<N_EDGES / 256, 256, 0, stream>>>(adj_row, adj_col, adj_vals,
                                                            cursor, ecol, evals);

    const int NT = N_NODES / 16;                 // 6250 row-tiles
    const int GT = (NT + 3) / 4;                 // 1563 blocks

    // proj
    proj_mfma_kernel<<<GT, 256, 0, stream>>>(node_features, Wpp, b_proj, h0);

    // layer 1
    spmm_bf16_kernel<<<N_NODES / 4, 256, 0, stream>>>(h0, hA, row_start, ecol, evals);
    mlp_mfma_kernel<<<GT, 256, 0, stream>>>(hA, W1p, b1, ln_g, ln_b, hB);

    // layer 2
    spmm_bf16_kernel<<<N_NODES / 4, 256, 0, stream>>>(hB, hA, row_start, ecol, evals);
    mlp_mfma_kernel<<<GT, 256, 0, stream>>>(hA, W2p, b2, ln_g, ln_b, hB);

    // scoring
    score_kernel<<<BATCH / 4, 256, 0, stream>>>(hB, h0, item_id_emb, user_emb,
                                                user_idx, item_idx, user_bias,
                                                item_bias, global_bias, outp);
}

// Round 4
// 487.221 us; speedup vs baseline: 1.6393x; 1.1544x over previous
//
#include <hip/hip_runtime.h>

#define N_NODES 100000
#define N_USERS 50000
#define F_DIM 256
#define H 128
#define N_EDGES 800000
#define BATCH 4096
#define LN_EPS 1e-5f

typedef __attribute__((ext_vector_type(8))) short short8_t;
typedef __attribute__((ext_vector_type(8))) __bf16 bf16x8;
typedef __attribute__((ext_vector_type(4))) float f32x4;

__device__ inline unsigned short f2bf(float f) {
    unsigned int u = __builtin_bit_cast(unsigned int, f);
    unsigned int r = (u + 0x7fffu + ((u >> 16) & 1u)) >> 16;
    return (unsigned short)r;
}
__device__ inline float bf_lo(unsigned int u) {
    unsigned int x = u << 16; return __builtin_bit_cast(float, x);
}
__device__ inline float bf_hi(unsigned int u) {
    unsigned int x = u & 0xFFFF0000u; return __builtin_bit_cast(float, x);
}

__device__ inline bf16x8 cvt8(const float4 a0, const float4 a1) {
    short8_t af;
    af[0] = (short)f2bf(a0.x); af[1] = (short)f2bf(a0.y);
    af[2] = (short)f2bf(a0.z); af[3] = (short)f2bf(a0.w);
    af[4] = (short)f2bf(a1.x); af[5] = (short)f2bf(a1.y);
    af[6] = (short)f2bf(a1.z); af[7] = (short)f2bf(a1.w);
    return __builtin_bit_cast(bf16x8, af);
}

// ---------------------------------------------------------------------------
// Pack all three weights into bf16 MFMA-fragment order in one kernel.
// Local idx decode: i=idx&7, lane=(idx>>3)&63, c=(idx>>9)&7, ks=idx>>12.
// frag elem i = W[c*16 + (lane&15)][ks*32 + (lane>>4)*8 + i]
// ---------------------------------------------------------------------------
__global__ void pack_all_kernel(const float* __restrict__ Wp_, const float* __restrict__ W1_,
                                const float* __restrict__ W2_, short* __restrict__ oP,
                                short* __restrict__ o1, short* __restrict__ o2) {
    int idx = blockIdx.x * 256 + threadIdx.x;      // 0 .. 65535
    const float* W; short* o; int K; int local;
    if (idx < 32768)      { W = Wp_; o = oP; K = 256; local = idx; }
    else if (idx < 49152) { W = W1_; o = o1; K = 128; local = idx - 32768; }
    else                  { W = W2_; o = o2; K = 128; local = idx - 49152; }
    int i    = local & 7;
    int lane = (local >> 3) & 63;
    int c    = (local >> 9) & 7;
    int ks   = local >> 12;
    int j = c * 16 + (lane & 15);
    int k = ks * 32 + (lane >> 4) * 8 + i;
    o[local] = (short)f2bf(W[j * K + k]);
}

// ---------------------------------------------------------------------------
// CSR build
// ---------------------------------------------------------------------------
__global__ void zero_ints_kernel(int* __restrict__ p, int n) {
    int i = blockIdx.x * 256 + threadIdx.x;
    if (i < n) p[i] = 0;
}

__global__ void count_edges_kernel(const int* __restrict__ row, int* __restrict__ counts) {
    int e = blockIdx.x * 256 + threadIdx.x;
    if (e < N_EDGES) atomicAdd(&counts[row[e]], 1);
}

__global__ void scan_pass1_kernel(const int* __restrict__ counts, int* __restrict__ out,
                                  int* __restrict__ blockSums, int n) {
    __shared__ int lds[256];
    int b = blockIdx.x;
    int t = threadIdx.x;
    int base = b * 1024 + t * 4;
    int v0 = (base + 0 < n) ? counts[base + 0] : 0;
    int v1 = (base + 1 < n) ? counts[base + 1] : 0;
    int v2 = (base + 2 < n) ? counts[base + 2] : 0;
    int v3 = (base + 3 < n) ? counts[base + 3] : 0;
    int tsum = v0 + v1 + v2 + v3;
    lds[t] = tsum;
    __syncthreads();
    for (int off = 1; off < 256; off <<= 1) {
        int x = 0;
        if (t >= off) x = lds[t - off];
        __syncthreads();
        lds[t] += x;
        __syncthreads();
    }
    int excl = (t > 0) ? lds[t - 1] : 0;
    if (t == 255) blockSums[b] = lds[255];
    int e0 = excl, e1 = e0 + v0, e2 = e1 + v1, e3 = e2 + v2;
    if (base + 0 < n) out[base + 0] = e0;
    if (base + 1 < n) out[base + 1] = e1;
    if (base + 2 < n) out[base + 2] = e2;
    if (base + 3 < n) out[base + 3] = e3;
}

// parallel single-block exclusive scan of nb (<=128) block sums
__global__ void scan_pass2_kernel(int* __restrict__ blockSums, int nb) {
    __shared__ int lds[128];
    int t = threadIdx.x;
    int v = (t < nb) ? blockSums[t] : 0;
    lds[t] = v;
    __syncthreads();
    for (int off = 1; off < 128; off <<= 1) {
        int x = (t >= off) ? lds[t - off] : 0;
        __syncthreads();
        lds[t] += x;
        __syncthreads();
    }
    if (t < nb) blockSums[t] = lds[t] - v;
}

__global__ void scan_pass3_kernel(int* __restrict__ row_start, int* __restrict__ cursor,
                                  const int* __restrict__ blockSums, int n) {
    int b = blockIdx.x;
    int t = threadIdx.x;
    int base = b * 1024 + t * 4;
    int add = blockSums[b];
    #pragma unroll
    for (int k = 0; k < 4; ++k) {
        int i = base + k;
        if (i < n) {
            int rs = row_start[i] + add;
            row_start[i] = rs;
            cursor[i] = rs;
        }
    }
}

__global__ void scatter_edges_kernel(const int* __restrict__ row, const int* __restrict__ col,
                                     const float* __restrict__ vals, int* __restrict__ cursor,
                                     int* __restrict__ ecol, float* __restrict__ evals) {
    int e = blockIdx.x * 256 + threadIdx.x;
    if (e >= N_EDGES) return;
    int r = row[e];
    int pos = atomicAdd(&cursor[r], 1);
    ecol[pos] = col[e];
    evals[pos] = vals[e];
}

// ---------------------------------------------------------------------------
// Proj: h0[n,j] = bf16( sum_f A[n,f]*Wp[j,f] + b[j] ).  MFMA 16x16x32 bf16.
// 2 row-tiles (32 rows) per wave: B-frags loaded once, used twice.
// ---------------------------------------------------------------------------
__global__ __launch_bounds__(256) void proj_mfma_kernel(
        const float* __restrict__ A, const short* __restrict__ Bp,
        const float* __restrict__ bias, unsigned short* __restrict__ out) {
    const int tid  = threadIdx.x;
    const int lane = tid & 63;
    const int wt = blockIdx.x * 8 + (tid >> 6) * 2;   // first of 2 tiles
    if (wt >= N_NODES / 16) return;                   // N/16 even => both valid
    const int lrow = lane & 15;
    const int lk   = lane >> 4;

    const short8_t* Bv = (const short8_t*)Bp;
    f32x4 acc0[8], acc1[8];
    #pragma unroll
    for (int c = 0; c < 8; ++c) { acc0[c] = (f32x4)(0.f); acc1[c] = (f32x4)(0.f); }

    const float* Ar0 = A + (size_t)(wt * 16 + lrow) * F_DIM + lk * 8;
    const float* Ar1 = Ar0 + 16 * F_DIM;
    #pragma unroll 2
    for (int ks = 0; ks < 8; ++ks) {
        const float4* a0p = (const float4*)(Ar0 + ks * 32);
        const float4* a1p = (const float4*)(Ar1 + ks * 32);
        bf16x8 av0 = cvt8(a0p[0], a0p[1]);
        bf16x8 av1 = cvt8(a1p[0], a1p[1]);
        const short8_t* bp = Bv + (size_t)(ks * 8) * 64 + lane;
        #pragma unroll
        for (int c = 0; c < 8; ++c) {
            bf16x8 bv = __builtin_bit_cast(bf16x8, bp[c * 64]);
            acc0[c] = __builtin_amdgcn_mfma_f32_16x16x32_bf16(av0, bv, acc0[c], 0, 0, 0);
            acc1[c] = __builtin_amdgcn_mfma_f32_16x16x32_bf16(av1, bv, acc1[c], 0, 0, 0);
        }
    }
    #pragma unroll
    for (int c = 0; c < 8; ++c) {
        float bj = bias[c * 16 + lrow];
        const int or0 = wt * 16 + lk * 4;
        #pragma unroll
        for (int r = 0; r < 4; ++r) {
            out[(size_t)(or0 + r) * H + c * 16 + lrow] = f2bf(acc0[c][r] + bj);
            out[(size_t)(or0 + 16 + r) * H + c * 16 + lrow] = f2bf(acc1[c][r] + bj);
        }
    }
}

// ---------------------------------------------------------------------------
// SPMM (bf16), 4-way ILP unroll: out[r,:] = bf16( sum_e val[e]*hin[col[e],:] )
// one wave per row; lane holds 2 bf16 (4B) -> 256B coalesced gather per edge.
// ---------------------------------------------------------------------------
__global__ __launch_bounds__(256) void spmm_bf16_kernel(
        const unsigned short* __restrict__ hin, unsigned short* __restrict__ hout,
        const int* __restrict__ row_start, const int* __restrict__ ecol,
        const float* __restrict__ evals) {
    const int wave = threadIdx.x >> 6;
    const int lane = threadIdx.x & 63;
    const int row = blockIdx.x * 4 + wave;
    if (row >= N_NODES) return;
    const int s = row_start[row];
    const int e = (row + 1 < N_NODES) ? row_start[row + 1] : N_EDGES;
    const unsigned int* h32 = (const unsigned int*)hin;

    float ax0 = 0.f, ay0 = 0.f, ax1 = 0.f, ay1 = 0.f;
    float ax2 = 0.f, ay2 = 0.f, ax3 = 0.f, ay3 = 0.f;
    int p = s;
    for (; p + 4 <= e; p += 4) {
        int c0 = ecol[p + 0], c1 = ecol[p + 1], c2 = ecol[p + 2], c3 = ecol[p + 3];
        float v0 = evals[p + 0], v1 = evals[p + 1], v2 = evals[p + 2], v3 = evals[p + 3];
        unsigned int b0 = h32[(size_t)c0 * 64 + lane];
        unsigned int b1 = h32[(size_t)c1 * 64 + lane];
        unsigned int b2 = h32[(size_t)c2 * 64 + lane];
        unsigned int b3 = h32[(size_t)c3 * 64 + lane];
        ax0 += v0 * bf_lo(b0); ay0 += v0 * bf_hi(b0);
        ax1 += v1 * bf_lo(b1); ay1 += v1 * bf_hi(b1);
        ax2 += v2 * bf_lo(b2); ay2 += v2 * bf_hi(b2);
        ax3 += v3 * bf_lo(b3); ay3 += v3 * bf_hi(b3);
    }
    for (; p < e; ++p) {
        int c = ecol[p];
        float vv = evals[p];
        unsigned int hb = h32[(size_t)c * 64 + lane];
        ax0 += vv * bf_lo(hb); ay0 += vv * bf_hi(hb);
    }
    float ax = (ax0 + ax1) + (ax2 + ax3);
    float ay = (ay0 + ay1) + (ay2 + ay3);
    unsigned int w = (unsigned int)f2bf(ax) | ((unsigned int)f2bf(ay) << 16);
    ((unsigned int*)hout)[(size_t)row * 64 + lane] = w;
}

// ---------------------------------------------------------------------------
// Fused MLP: out = bf16( LN(relu(X @ W.T + b)) * g + beta ).  MFMA, K=128.
// 2 row-tiles (32 rows) per wave.
// ---------------------------------------------------------------------------
__device__ inline void mlp_epilogue(f32x4* acc, const float* __restrict__ bias,
                                    const float* __restrict__ g, const float* __restrict__ beta,
                                    unsigned short* __restrict__ out,
                                    int row0, int lrow, int lk) {
    float s1[4] = {0.f, 0.f, 0.f, 0.f};
    float s2[4] = {0.f, 0.f, 0.f, 0.f};
    #pragma unroll
    for (int c = 0; c < 8; ++c) {
        float bj = bias[c * 16 + lrow];
        #pragma unroll
        for (int r = 0; r < 4; ++r) {
            float x = fmaxf(acc[c][r] + bj, 0.f);
            acc[c][r] = x;
            s1[r] += x;
            s2[r] += x * x;
        }
    }
    #pragma unroll
    for (int r = 0; r < 4; ++r) {
        #pragma unroll
        for (int off = 1; off < 16; off <<= 1) {
            s1[r] += __shfl_xor(s1[r], off);
            s2[r] += __shfl_xor(s2[r], off);
        }
    }
    float mu[4], rr[4];
    #pragma unroll
    for (int r = 0; r < 4; ++r) {
        mu[r] = s1[r] * (1.f / 128.f);
        float var = s2[r] * (1.f / 128.f) - mu[r] * mu[r];
        rr[r] = rsqrtf(var + LN_EPS);
    }
    const int orow = row0 + lk * 4;
    #pragma unroll
    for (int c = 0; c < 8; ++c) {
        float gj  = g[c * 16 + lrow];
        float bj2 = beta[c * 16 + lrow];
        #pragma unroll
        for (int r = 0; r < 4; ++r)
            out[(size_t)(orow + r) * H + c * 16 + lrow] =
                f2bf((acc[c][r] - mu[r]) * rr[r] * gj + bj2);
    }
}

__global__ __launch_bounds__(256) void mlp_mfma_kernel(
        const unsigned short* __restrict__ X, const short* __restrict__ Bp,
        const float* __restrict__ bias, const float* __restrict__ g,
        const float* __restrict__ beta, unsigned short* __restrict__ out) {
    const int tid  = threadIdx.x;
    const int lane = tid & 63;
    const int wt = blockIdx.x * 8 + (tid >> 6) * 2;   // first of 2 tiles
    if (wt >= N_NODES / 16) return;
    const int lrow = lane & 15;
    const int lk   = lane >> 4;

    const short8_t* Bv = (const short8_t*)Bp;
    const short8_t* Xv0 = (const short8_t*)(X + (size_t)(wt * 16 + lrow) * H + lk * 8);
    const short8_t* Xv1 = (const short8_t*)(X + (size_t)((wt + 1) * 16 + lrow) * H + lk * 8);

    f32x4 acc0[8], acc1[8];
    #pragma unroll
    for (int c = 0; c < 8; ++c) { acc0[c] = (f32x4)(0.f); acc1[c] = (f32x4)(0.f); }

    #pragma unroll
    for (int ks = 0; ks < 4; ++ks) {
        bf16x8 av0 = __builtin_bit_cast(bf16x8, Xv0[ks * 4]);
        bf16x8 av1 = __builtin_bit_cast(bf16x8, Xv1[ks * 4]);
        const short8_t* bp = Bv + (size_t)(ks * 8) * 64 + lane;
        #pragma unroll
        for (int c = 0; c < 8; ++c) {
            bf16x8 bv = __builtin_bit_cast(bf16x8, bp[c * 64]);
            acc0[c] = __builtin_amdgcn_mfma_f32_16x16x32_bf16(av0, bv, acc0[c], 0, 0, 0);
            acc1[c] = __builtin_amdgcn_mfma_f32_16x16x32_bf16(av1, bv, acc1[c], 0, 0, 0);
        }
    }
    mlp_epilogue(acc0, bias, g, beta, out, wt * 16, lrow, lk);
    mlp_epilogue(acc1, bias, g, beta, out, (wt + 1) * 16, lrow, lk);
}

// ---------------------------------------------------------------------------
// Scoring: out[b] = gb + ub[u] + ib[i] + dot(uemb[u], hf[i] + h0[i] + iie[i])
// ---------------------------------------------------------------------------
__global__ __launch_bounds__(256) void score_kernel(
        const unsigned short* __restrict__ hf, const unsigned short* __restrict__ h0,
        const float* __restrict__ iie, const float* __restrict__ uemb,
        const int* __restrict__ uidx, const int* __restrict__ iidx,
        const float* __restrict__ ubias, const float* __restrict__ ibias,
        const float* __restrict__ gbias, float* __restrict__ out) {
    const int wave = threadIdx.x >> 6;
    const int lane = threadIdx.x & 63;
    const int b = blockIdx.x * 4 + wave;
    if (b >= BATCH) return;
    const int u  = uidx[b];
    const int it = iidx[b];
    unsigned int b1 = ((const unsigned int*)hf)[(size_t)it * 64 + lane];
    unsigned int b2 = ((const unsigned int*)h0)[(size_t)it * 64 + lane];
    float2 x3 = ((const float2*)(iie + (size_t)it * H))[lane];
    float2 a  = ((const float2*)(uemb + (size_t)u * H))[lane];
    float p = a.x * (bf_lo(b1) + bf_lo(b2) + x3.x) +
              a.y * (bf_hi(b1) + bf_hi(b2) + x3.y);
    #pragma unroll
    for (int off = 32; off > 0; off >>= 1) p += __shfl_xor(p, off);
    if (lane == 0) out[b] = gbias[0] + ubias[u] + ibias[it] + p;
}

// ---------------------------------------------------------------------------

extern "C" void kernel_launch(void* const* d_in, const int* in_sizes, int n_in,
                              void* d_out, int out_size, void* d_ws, size_t ws_size,
                              hipStream_t stream) {
    const float* node_features = (const float*)d_in[0];
    const int*   adj_row       = (const int*)d_in[1];
    const int*   adj_col       = (const int*)d_in[2];
    const float* adj_vals      = (const float*)d_in[3];
    const int*   user_idx      = (const int*)d_in[4];
    const int*   item_idx      = (const int*)d_in[5];
    const float* W_proj        = (const float*)d_in[6];
    const float* b_proj        = (const float*)d_in[7];
    const float* W1            = (const float*)d_in[8];
    const float* b1            = (const float*)d_in[9];
    const float* W2            = (const float*)d_in[10];
    const float* b2            = (const float*)d_in[11];
    const float* ln_g          = (const float*)d_in[12];
    const float* ln_b          = (const float*)d_in[13];
    const float* user_emb      = (const float*)d_in[14];
    const float* item_id_emb   = (const float*)d_in[15];
    const float* user_bias     = (const float*)d_in[16];
    const float* item_bias     = (const float*)d_in[17];
    const float* global_bias   = (const float*)d_in[18];
    float* outp = (float*)d_out;

    char* ws = (char*)d_ws;
    size_t off = 0;
    auto alloc = [&](size_t bytes) -> void* {
        void* p = ws + off;
        off = (off + bytes + 255) & ~(size_t)255;
        return p;
    };

    unsigned short* h0 = (unsigned short*)alloc(sizeof(short) * (size_t)N_NODES * H);
    unsigned short* hA = (unsigned short*)alloc(sizeof(short) * (size_t)N_NODES * H);
    unsigned short* hB = (unsigned short*)alloc(sizeof(short) * (size_t)N_NODES * H);
    short* Wpp = (short*)alloc(sizeof(short) * F_DIM * H);
    short* W1p = (short*)alloc(sizeof(short) * H * H);
    short* W2p = (short*)alloc(sizeof(short) * H * H);
    int* counts    = (int*)alloc(sizeof(int) * N_NODES);
    int* row_start = (int*)alloc(sizeof(int) * N_NODES);
    int* cursor    = (int*)alloc(sizeof(int) * N_NODES);
    int* blockSums = (int*)alloc(sizeof(int) * 128);
    int* ecol      = (int*)alloc(sizeof(int) * N_EDGES);
    float* evals   = (float*)alloc(sizeof(float) * N_EDGES);

    const int NB = (N_NODES + 1023) / 1024;  // 98

    // weight packing (one kernel, bf16 fragment order)
    pack_all_kernel<<<256, 256, 0, stream>>>(W_proj, W1, W2, Wpp, W1p, W2p);

    // CSR build
    zero_ints_kernel<<<(N_NODES + 255) / 256, 256, 0, stream>>>(counts, N_NODES);
    count_edges_kernel<<<N_EDGES / 256, 256, 0, stream>>>(adj_row, counts);
    scan_pass1_kernel<<<NB, 256, 0, stream>>>(counts, row_start, blockSums, N_NODES);
    scan_pass2_kernel<<<1, 128, 0, stream>>>(blockSums, NB);
    scan_pass3_kernel<<<NB, 256, 0, stream>>>(row_start, cursor, blockSums, N_NODES);
    scatter_edges_kernel<<<N_EDGES / 256, 256, 0, stream>>>(adj_row, adj_col, adj_vals,
                                                            cursor, ecol, evals);

    const int NT = N_NODES / 16;                 // 6250 row-tiles
    const int GT8 = (NT + 7) / 8;                // 782 blocks (8 tiles per block)

    // proj
    proj_mfma_kernel<<<GT8, 256, 0, stream>>>(node_features, Wpp, b_proj, h0);

    // layer 1
    spmm_bf16_kernel<<<N_NODES / 4, 256, 0, stream>>>(h0, hA, row_start, ecol, evals);
    mlp_mfma_kernel<<<GT8, 256, 0, stream>>>(hA, W1p, b1, ln_g, ln_b, hB);

    // layer 2
    spmm_bf16_kernel<<<N_NODES / 4, 256, 0, stream>>>(hB, hA, row_start, ecol, evals);
    mlp_mfma_kernel<<<GT8, 256, 0, stream>>>(hA, W2p, b2, ln_g, ln_b, hB);

    // scoring
    score_kernel<<<BATCH / 4, 256, 0, stream>>>(hB, h0, item_id_emb, user_emb,
                                                user_idx, item_idx, user_bias,
                                                item_bias, global_bias, outp);
}

// Round 5
// 445.223 us; speedup vs baseline: 1.7939x; 1.0943x over previous
//
#include <hip/hip_runtime.h>

#define N_NODES 100000
#define N_USERS 50000
#define F_DIM 256
#define H 128
#define N_EDGES 800000
#define BATCH 4096
#define LN_EPS 1e-5f

typedef __attribute__((ext_vector_type(8))) short short8_t;
typedef __attribute__((ext_vector_type(8))) __bf16 bf16x8;
typedef __attribute__((ext_vector_type(4))) float f32x4;

__device__ inline unsigned short f2bf(float f) {
    unsigned int u = __builtin_bit_cast(unsigned int, f);
    unsigned int r = (u + 0x7fffu + ((u >> 16) & 1u)) >> 16;
    return (unsigned short)r;
}
__device__ inline float bf_lo(unsigned int u) {
    unsigned int x = u << 16; return __builtin_bit_cast(float, x);
}
__device__ inline float bf_hi(unsigned int u) {
    unsigned int x = u & 0xFFFF0000u; return __builtin_bit_cast(float, x);
}

__device__ inline bf16x8 cvt8(const float4 a0, const float4 a1) {
    short8_t af;
    af[0] = (short)f2bf(a0.x); af[1] = (short)f2bf(a0.y);
    af[2] = (short)f2bf(a0.z); af[3] = (short)f2bf(a0.w);
    af[4] = (short)f2bf(a1.x); af[5] = (short)f2bf(a1.y);
    af[6] = (short)f2bf(a1.z); af[7] = (short)f2bf(a1.w);
    return __builtin_bit_cast(bf16x8, af);
}

// ---------------------------------------------------------------------------
// Pack all three weights into bf16 MFMA-fragment order in one kernel.
// frag elem i = W[c*16 + (lane&15)][ks*32 + (lane>>4)*8 + i]
// ---------------------------------------------------------------------------
__global__ void pack_all_kernel(const float* __restrict__ Wp_, const float* __restrict__ W1_,
                                const float* __restrict__ W2_, short* __restrict__ oP,
                                short* __restrict__ o1, short* __restrict__ o2) {
    int idx = blockIdx.x * 256 + threadIdx.x;      // 0 .. 65535
    const float* W; short* o; int K; int local;
    if (idx < 32768)      { W = Wp_; o = oP; K = 256; local = idx; }
    else if (idx < 49152) { W = W1_; o = o1; K = 128; local = idx - 32768; }
    else                  { W = W2_; o = o2; K = 128; local = idx - 49152; }
    int i    = local & 7;
    int lane = (local >> 3) & 63;
    int c    = (local >> 9) & 7;
    int ks   = local >> 12;
    int j = c * 16 + (lane & 15);
    int k = ks * 32 + (lane >> 4) * 8 + i;
    o[local] = (short)f2bf(W[j * K + k]);
}

// ---------------------------------------------------------------------------
// CSR build
// ---------------------------------------------------------------------------
__global__ void zero_ints_kernel(int* __restrict__ p, int n) {
    int i = blockIdx.x * 256 + threadIdx.x;
    if (i < n) p[i] = 0;
}

__global__ void count_edges_kernel(const int* __restrict__ row, int* __restrict__ counts) {
    int e = blockIdx.x * 256 + threadIdx.x;
    if (e < N_EDGES) atomicAdd(&counts[row[e]], 1);
}

__global__ void scan_pass1_kernel(const int* __restrict__ counts, int* __restrict__ out,
                                  int* __restrict__ blockSums, int n) {
    __shared__ int lds[256];
    int b = blockIdx.x;
    int t = threadIdx.x;
    int base = b * 1024 + t * 4;
    int v0 = (base + 0 < n) ? counts[base + 0] : 0;
    int v1 = (base + 1 < n) ? counts[base + 1] : 0;
    int v2 = (base + 2 < n) ? counts[base + 2] : 0;
    int v3 = (base + 3 < n) ? counts[base + 3] : 0;
    int tsum = v0 + v1 + v2 + v3;
    lds[t] = tsum;
    __syncthreads();
    for (int off = 1; off < 256; off <<= 1) {
        int x = 0;
        if (t >= off) x = lds[t - off];
        __syncthreads();
        lds[t] += x;
        __syncthreads();
    }
    int excl = (t > 0) ? lds[t - 1] : 0;
    if (t == 255) blockSums[b] = lds[255];
    int e0 = excl, e1 = e0 + v0, e2 = e1 + v1, e3 = e2 + v2;
    if (base + 0 < n) out[base + 0] = e0;
    if (base + 1 < n) out[base + 1] = e1;
    if (base + 2 < n) out[base + 2] = e2;
    if (base + 3 < n) out[base + 3] = e3;
}

// parallel single-block exclusive scan of nb (<=128) block sums
__global__ void scan_pass2_kernel(int* __restrict__ blockSums, int nb) {
    __shared__ int lds[128];
    int t = threadIdx.x;
    int v = (t < nb) ? blockSums[t] : 0;
    lds[t] = v;
    __syncthreads();
    for (int off = 1; off < 128; off <<= 1) {
        int x = (t >= off) ? lds[t - off] : 0;
        __syncthreads();
        lds[t] += x;
        __syncthreads();
    }
    if (t < nb) blockSums[t] = lds[t] - v;
}

__global__ void scan_pass3_kernel(int* __restrict__ row_start, int* __restrict__ cursor,
                                  const int* __restrict__ blockSums, int n) {
    int b = blockIdx.x;
    int t = threadIdx.x;
    int base = b * 1024 + t * 4;
    int add = blockSums[b];
    #pragma unroll
    for (int k = 0; k < 4; ++k) {
        int i = base + k;
        if (i < n) {
            int rs = row_start[i] + add;
            row_start[i] = rs;
            cursor[i] = rs;
        }
    }
}

__global__ void scatter_edges_kernel(const int* __restrict__ row, const int* __restrict__ col,
                                     const float* __restrict__ vals, int* __restrict__ cursor,
                                     int* __restrict__ ecol, float* __restrict__ evals) {
    int e = blockIdx.x * 256 + threadIdx.x;
    if (e >= N_EDGES) return;
    int r = row[e];
    int pos = atomicAdd(&cursor[r], 1);
    ecol[pos] = col[e];
    evals[pos] = vals[e];
}

// ---------------------------------------------------------------------------
// Proj: h0[n,j] = bf16( sum_f A[n,f]*Wp[j,f] + b[j] ).  MFMA 16x16x32 bf16.
// One 16-row tile per wave; ALL 16 A-loads (dwordx4) issued upfront.
// ---------------------------------------------------------------------------
__global__ __launch_bounds__(256) void proj_mfma_kernel(
        const float* __restrict__ A, const short* __restrict__ Bp,
        const float* __restrict__ bias, unsigned short* __restrict__ out) {
    const int tid  = threadIdx.x;
    const int lane = tid & 63;
    const int tile = blockIdx.x * 4 + (tid >> 6);
    if (tile >= N_NODES / 16) return;
    const int row0 = tile * 16;
    const int lrow = lane & 15;
    const int lk   = lane >> 4;

    // preload the whole A slab for this wave: 16 outstanding dwordx4
    const float4* Ap = (const float4*)(A + (size_t)(row0 + lrow) * F_DIM + lk * 8);
    float4 a[16];
    #pragma unroll
    for (int ks = 0; ks < 8; ++ks) {
        a[2 * ks]     = Ap[ks * 8];
        a[2 * ks + 1] = Ap[ks * 8 + 1];
    }

    const short8_t* Bv = (const short8_t*)Bp;
    f32x4 acc[8];
    #pragma unroll
    for (int c = 0; c < 8; ++c) acc[c] = (f32x4)(0.f);

    #pragma unroll
    for (int ks = 0; ks < 8; ++ks) {
        bf16x8 av = cvt8(a[2 * ks], a[2 * ks + 1]);
        const short8_t* bp = Bv + (size_t)(ks * 8) * 64 + lane;
        #pragma unroll
        for (int c = 0; c < 8; ++c) {
            bf16x8 bv = __builtin_bit_cast(bf16x8, bp[c * 64]);
            acc[c] = __builtin_amdgcn_mfma_f32_16x16x32_bf16(av, bv, acc[c], 0, 0, 0);
        }
    }
    const int orow = row0 + lk * 4;
    #pragma unroll
    for (int c = 0; c < 8; ++c) {
        float bj = bias[c * 16 + lrow];
        #pragma unroll
        for (int r = 0; r < 4; ++r)
            out[(size_t)(orow + r) * H + c * 16 + lrow] = f2bf(acc[c][r] + bj);
    }
}

// ---------------------------------------------------------------------------
// SPMM (bf16): out[r,:] = bf16( sum_e val[e]*hin[col[e],:] )
// One wave per row. Row metadata (up to 64 edges) loaded ONCE lane-parallel,
// broadcast via shfl; gathers issued in padded quads (v=0 slots contribute 0),
// 4 independent acc pairs + unroll 2 -> up to 8 gathers in flight.
// ---------------------------------------------------------------------------
__global__ __launch_bounds__(256) void spmm_bf16_kernel(
        const unsigned short* __restrict__ hin, unsigned short* __restrict__ hout,
        const int* __restrict__ row_start, const int* __restrict__ ecol,
        const float* __restrict__ evals) {
    const int wave = threadIdx.x >> 6;
    const int lane = threadIdx.x & 63;
    const int row = blockIdx.x * 4 + wave;
    if (row >= N_NODES) return;
    const int s = row_start[row];
    const int e = (row + 1 < N_NODES) ? row_start[row + 1] : N_EDGES;
    const int deg = e - s;
    const unsigned int* h32 = (const unsigned int*)hin;

    // one-shot metadata load: lane holds edge s+lane (zero weight if past end)
    int mi = s + lane;
    int idxm = (mi < N_EDGES) ? mi : (N_EDGES - 1);
    int   c_all = ecol[idxm];
    float v_all = (mi < e) ? evals[idxm] : 0.f;

    float ax0 = 0.f, ay0 = 0.f, ax1 = 0.f, ay1 = 0.f;
    float ax2 = 0.f, ay2 = 0.f, ax3 = 0.f, ay3 = 0.f;

    const int dmain = (deg < 64) ? deg : 64;
    #pragma unroll 2
    for (int p = 0; p < dmain; p += 4) {      // p <= 60, so p+3 <= 63: shfl idx safe
        int   c0 = __shfl(c_all, p + 0); float v0 = __shfl(v_all, p + 0);
        int   c1 = __shfl(c_all, p + 1); float v1 = __shfl(v_all, p + 1);
        int   c2 = __shfl(c_all, p + 2); float v2 = __shfl(v_all, p + 2);
        int   c3 = __shfl(c_all, p + 3); float v3 = __shfl(v_all, p + 3);
        unsigned int b0 = h32[(size_t)c0 * 64 + lane];
        unsigned int b1 = h32[(size_t)c1 * 64 + lane];
        unsigned int b2 = h32[(size_t)c2 * 64 + lane];
        unsigned int b3 = h32[(size_t)c3 * 64 + lane];
        ax0 += v0 * bf_lo(b0); ay0 += v0 * bf_hi(b0);
        ax1 += v1 * bf_lo(b1); ay1 += v1 * bf_hi(b1);
        ax2 += v2 * bf_lo(b2); ay2 += v2 * bf_hi(b2);
        ax3 += v3 * bf_lo(b3); ay3 += v3 * bf_hi(b3);
    }
    // safety tail for deg > 64 (essentially never at E[deg]=8)
    for (int p = s + 64; p < e; ++p) {
        int c = ecol[p];
        float vv = evals[p];
        unsigned int hb = h32[(size_t)c * 64 + lane];
        ax0 += vv * bf_lo(hb); ay0 += vv * bf_hi(hb);
    }
    float ax = (ax0 + ax1) + (ax2 + ax3);
    float ay = (ay0 + ay1) + (ay2 + ay3);
    unsigned int w = (unsigned int)f2bf(ax) | ((unsigned int)f2bf(ay) << 16);
    ((unsigned int*)hout)[(size_t)row * 64 + lane] = w;
}

// ---------------------------------------------------------------------------
// Fused MLP: out = bf16( LN(relu(X @ W.T + b)) * g + beta ).  MFMA, K=128.
// One 16-row tile per wave; X preloaded (4 outstanding dwordx4).
// ---------------------------------------------------------------------------
__device__ inline void mlp_epilogue(f32x4* acc, const float* __restrict__ bias,
                                    const float* __restrict__ g, const float* __restrict__ beta,
                                    unsigned short* __restrict__ out,
                                    int row0, int lrow, int lk) {
    float s1[4] = {0.f, 0.f, 0.f, 0.f};
    float s2[4] = {0.f, 0.f, 0.f, 0.f};
    #pragma unroll
    for (int c = 0; c < 8; ++c) {
        float bj = bias[c * 16 + lrow];
        #pragma unroll
        for (int r = 0; r < 4; ++r) {
            float x = fmaxf(acc[c][r] + bj, 0.f);
            acc[c][r] = x;
            s1[r] += x;
            s2[r] += x * x;
        }
    }
    #pragma unroll
    for (int r = 0; r < 4; ++r) {
        #pragma unroll
        for (int off = 1; off < 16; off <<= 1) {
            s1[r] += __shfl_xor(s1[r], off);
            s2[r] += __shfl_xor(s2[r], off);
        }
    }
    float mu[4], rr[4];
    #pragma unroll
    for (int r = 0; r < 4; ++r) {
        mu[r] = s1[r] * (1.f / 128.f);
        float var = s2[r] * (1.f / 128.f) - mu[r] * mu[r];
        rr[r] = rsqrtf(var + LN_EPS);
    }
    const int orow = row0 + lk * 4;
    #pragma unroll
    for (int c = 0; c < 8; ++c) {
        float gj  = g[c * 16 + lrow];
        float bj2 = beta[c * 16 + lrow];
        #pragma unroll
        for (int r = 0; r < 4; ++r)
            out[(size_t)(orow + r) * H + c * 16 + lrow] =
                f2bf((acc[c][r] - mu[r]) * rr[r] * gj + bj2);
    }
}

__global__ __launch_bounds__(256) void mlp_mfma_kernel(
        const unsigned short* __restrict__ X, const short* __restrict__ Bp,
        const float* __restrict__ bias, const float* __restrict__ g,
        const float* __restrict__ beta, unsigned short* __restrict__ out) {
    const int tid  = threadIdx.x;
    const int lane = tid & 63;
    const int tile = blockIdx.x * 4 + (tid >> 6);
    if (tile >= N_NODES / 16) return;
    const int row0 = tile * 16;
    const int lrow = lane & 15;
    const int lk   = lane >> 4;

    const short8_t* Xv = (const short8_t*)(X + (size_t)(row0 + lrow) * H + lk * 8);
    short8_t x[4];
    #pragma unroll
    for (int ks = 0; ks < 4; ++ks) x[ks] = Xv[ks * 4];

    const short8_t* Bv = (const short8_t*)Bp;
    f32x4 acc[8];
    #pragma unroll
    for (int c = 0; c < 8; ++c) acc[c] = (f32x4)(0.f);

    #pragma unroll
    for (int ks = 0; ks < 4; ++ks) {
        bf16x8 av = __builtin_bit_cast(bf16x8, x[ks]);
        const short8_t* bp = Bv + (size_t)(ks * 8) * 64 + lane;
        #pragma unroll
        for (int c = 0; c < 8; ++c) {
            bf16x8 bv = __builtin_bit_cast(bf16x8, bp[c * 64]);
            acc[c] = __builtin_amdgcn_mfma_f32_16x16x32_bf16(av, bv, acc[c], 0, 0, 0);
        }
    }
    mlp_epilogue(acc, bias, g, beta, out, row0, lrow, lk);
}

// ---------------------------------------------------------------------------
// Scoring: out[b] = gb + ub[u] + ib[i] + dot(uemb[u], hf[i] + h0[i] + iie[i])
// ---------------------------------------------------------------------------
__global__ __launch_bounds__(256) void score_kernel(
        const unsigned short* __restrict__ hf, const unsigned short* __restrict__ h0,
        const float* __restrict__ iie, const float* __restrict__ uemb,
        const int* __restrict__ uidx, const int* __restrict__ iidx,
        const float* __restrict__ ubias, const float* __restrict__ ibias,
        const float* __restrict__ gbias, float* __restrict__ out) {
    const int wave = threadIdx.x >> 6;
    const int lane = threadIdx.x & 63;
    const int b = blockIdx.x * 4 + wave;
    if (b >= BATCH) return;
    const int u  = uidx[b];
    const int it = iidx[b];
    unsigned int b1 = ((const unsigned int*)hf)[(size_t)it * 64 + lane];
    unsigned int b2 = ((const unsigned int*)h0)[(size_t)it * 64 + lane];
    float2 x3 = ((const float2*)(iie + (size_t)it * H))[lane];
    float2 a  = ((const float2*)(uemb + (size_t)u * H))[lane];
    float p = a.x * (bf_lo(b1) + bf_lo(b2) + x3.x) +
              a.y * (bf_hi(b1) + bf_hi(b2) + x3.y);
    #pragma unroll
    for (int off = 32; off > 0; off >>= 1) p += __shfl_xor(p, off);
    if (lane == 0) out[b] = gbias[0] + ubias[u] + ibias[it] + p;
}

// ---------------------------------------------------------------------------

extern "C" void kernel_launch(void* const* d_in, const int* in_sizes, int n_in,
                              void* d_out, int out_size, void* d_ws, size_t ws_size,
                              hipStream_t stream) {
    const float* node_features = (const float*)d_in[0];
    const int*   adj_row       = (const int*)d_in[1];
    const int*   adj_col       = (const int*)d_in[2];
    const float* adj_vals      = (const float*)d_in[3];
    const int*   user_idx      = (const int*)d_in[4];
    const int*   item_idx      = (const int*)d_in[5];
    const float* W_proj        = (const float*)d_in[6];
    const float* b_proj        = (const float*)d_in[7];
    const float* W1            = (const float*)d_in[8];
    const float* b1            = (const float*)d_in[9];
    const float* W2            = (const float*)d_in[10];
    const float* b2            = (const float*)d_in[11];
    const float* ln_g          = (const float*)d_in[12];
    const float* ln_b          = (const float*)d_in[13];
    const float* user_emb      = (const float*)d_in[14];
    const float* item_id_emb   = (const float*)d_in[15];
    const float* user_bias     = (const float*)d_in[16];
    const float* item_bias     = (const float*)d_in[17];
    const float* global_bias   = (const float*)d_in[18];
    float* outp = (float*)d_out;

    char* ws = (char*)d_ws;
    size_t off = 0;
    auto alloc = [&](size_t bytes) -> void* {
        void* p = ws + off;
        off = (off + bytes + 255) & ~(size_t)255;
        return p;
    };

    unsigned short* h0 = (unsigned short*)alloc(sizeof(short) * (size_t)N_NODES * H);
    unsigned short* hA = (unsigned short*)alloc(sizeof(short) * (size_t)N_NODES * H);
    unsigned short* hB = (unsigned short*)alloc(sizeof(short) * (size_t)N_NODES * H);
    short* Wpp = (short*)alloc(sizeof(short) * F_DIM * H);
    short* W1p = (short*)alloc(sizeof(short) * H * H);
    short* W2p = (short*)alloc(sizeof(short) * H * H);
    int* counts    = (int*)alloc(sizeof(int) * N_NODES);
    int* row_start = (int*)alloc(sizeof(int) * N_NODES);
    int* cursor    = (int*)alloc(sizeof(int) * N_NODES);
    int* blockSums = (int*)alloc(sizeof(int) * 128);
    int* ecol      = (int*)alloc(sizeof(int) * N_EDGES);
    float* evals   = (float*)alloc(sizeof(float) * N_EDGES);

    const int NB = (N_NODES + 1023) / 1024;  // 98

    // weight packing (one kernel, bf16 fragment order)
    pack_all_kernel<<<256, 256, 0, stream>>>(W_proj, W1, W2, Wpp, W1p, W2p);

    // CSR build
    zero_ints_kernel<<<(N_NODES + 255) / 256, 256, 0, stream>>>(counts, N_NODES);
    count_edges_kernel<<<N_EDGES / 256, 256, 0, stream>>>(adj_row, counts);
    scan_pass1_kernel<<<NB, 256, 0, stream>>>(counts, row_start, blockSums, N_NODES);
    scan_pass2_kernel<<<1, 128, 0, stream>>>(blockSums, NB);
    scan_pass3_kernel<<<NB, 256, 0, stream>>>(row_start, cursor, blockSums, N_NODES);
    scatter_edges_kernel<<<N_EDGES / 256, 256, 0, stream>>>(adj_row, adj_col, adj_vals,
                                                            cursor, ecol, evals);

    const int NT = N_NODES / 16;                 // 6250 row-tiles
    const int GT4 = (NT + 3) / 4;                // 1563 blocks (1 tile per wave)

    // proj
    proj_mfma_kernel<<<GT4, 256, 0, stream>>>(node_features, Wpp, b_proj, h0);

    // layer 1
    spmm_bf16_kernel<<<N_NODES / 4, 256, 0, stream>>>(h0, hA, row_start, ecol, evals);
    mlp_mfma_kernel<<<GT4, 256, 0, stream>>>(hA, W1p, b1, ln_g, ln_b, hB);

    // layer 2
    spmm_bf16_kernel<<<N_NODES / 4, 256, 0, stream>>>(hB, hA, row_start, ecol, evals);
    mlp_mfma_kernel<<<GT4, 256, 0, stream>>>(hA, W2p, b2, ln_g, ln_b, hB);

    // scoring
    score_kernel<<<BATCH / 4, 256, 0, stream>>>(hB, h0, item_id_emb, user_emb,
                                                user_idx, item_idx, user_bias,
                                                item_bias, global_bias, outp);
}